// Round 1
// baseline (769.940 us; speedup 1.0000x reference)
//
#include <hip/hip_runtime.h>
#include <limits.h>

#define NUM_Q    4096
#define MAX_STEP 256
#define BATCH    64
#define TWOQ     8192   // 2*NUM_Q

// Kernel 1: for each (b,s) row of batch [B,S,2Q], find the index of the single
// nonzero entry (one-hot), or -1 if the row is all zero (leading padding).
// qa[b*MAX_STEP + s] = idx in [0, 8192) or -1.
__global__ void __launch_bounds__(256) find_onehot_kernel(
        const float* __restrict__ batch, int* __restrict__ qa) {
    const int row = blockIdx.x;  // 0 .. B*S-1
    const float4* rp = (const float4*)(batch + (size_t)row * TWOQ);

    __shared__ int found;
    if (threadIdx.x == 0) found = -1;
    __syncthreads();

    // 256 threads * 4 floats = 1024 floats per iter; 8 iters cover 8192.
    #pragma unroll
    for (int it = 0; it < 8; ++it) {
        const int vi = it * 256 + threadIdx.x;   // float4 index within row
        const float4 v = rp[vi];
        if (v.x != 0.f || v.y != 0.f || v.z != 0.f || v.w != 0.f) {
            const int base = vi * 4;
            int idx = (v.x != 0.f) ? base
                    : (v.y != 0.f) ? base + 1
                    : (v.z != 0.f) ? base + 2
                                   : base + 3;
            found = idx;   // exactly one nonzero per row -> single writer, no race
        }
    }
    __syncthreads();
    if (threadIdx.x == 0) qa[row] = found;
}

__device__ __forceinline__ float bce(float p, float a) {
    // matches torch BCELoss: logs clamped at -100. logf(0) = -inf -> clamped.
    float lp  = fmaxf(logf(p), -100.0f);
    float l1p = fmaxf(log1pf(-p), -100.0f);
    return -(a * lp + (1.0f - a) * l1p);
}

// Kernel 2: one block per student b. Finds trim index i, sums BCE over s>=i,
// adds tail term, divides by n = 256 - i, atomically accumulates into out[0].
__global__ void __launch_bounds__(256) loss_kernel(
        const float* __restrict__ pred,
        const float* __restrict__ target_q,
        const float* __restrict__ target_label,
        const int* __restrict__ qa,
        float* __restrict__ out) {
    const int b = blockIdx.x;
    const int t = threadIdx.x;
    const int SM1 = MAX_STEP - 1;  // 255

    __shared__ int   smin[256];
    __shared__ float ssum[256];

    // Fetch this thread's step info: step s = t (covers 0..254), uses qa[b, s+1].
    int   idx = -1;
    float p   = 0.0f;
    float a   = 0.0f;
    if (t < SM1) {
        idx = qa[b * MAX_STEP + t + 1];
        if (idx >= 0) {
            const int qid = idx & (NUM_Q - 1);
            p = pred[((size_t)b * MAX_STEP + t) * NUM_Q + qid];
            a = (idx < NUM_Q) ? 1.0f : 0.0f;
        }
    }

    // i = first s with p > 0  <=>  first s with valid one-hot at s+1
    // (pred >= 0.01 so any valid gather gives p > 0). argmax of all-false -> 0.
    smin[t] = (t < SM1 && idx >= 0 && p > 0.0f) ? t : INT_MAX;
    __syncthreads();
    #pragma unroll
    for (int off = 128; off > 0; off >>= 1) {
        if (t < off) smin[t] = min(smin[t], smin[t + off]);
        __syncthreads();
    }
    const int i0 = (smin[0] == INT_MAX) ? 0 : smin[0];

    // seq_loss: sum BCE over masked steps s >= i0
    float v = 0.0f;
    if (t < SM1 && t >= i0) v = bce(p, a);
    ssum[t] = v;
    __syncthreads();
    #pragma unroll
    for (int off = 128; off > 0; off >>= 1) {
        if (t < off) ssum[t] += ssum[t + off];
        __syncthreads();
    }

    if (t == 0) {
        const float tail = bce(target_q[b], target_label[b]);
        const float n = (float)(MAX_STEP - i0);  // (S-1) - i + 1
        atomicAdd(out, (ssum[0] + tail) / n);
    }
}

extern "C" void kernel_launch(void* const* d_in, const int* in_sizes, int n_in,
                              void* d_out, int out_size, void* d_ws, size_t ws_size,
                              hipStream_t stream) {
    const float* pred         = (const float*)d_in[0];  // [B,S,Q]
    const float* target_q     = (const float*)d_in[1];  // [B,1]
    const float* batch        = (const float*)d_in[2];  // [B,S,2Q]
    const float* target_label = (const float*)d_in[3];  // [B]
    float* out = (float*)d_out;
    int*   qa  = (int*)d_ws;  // B*MAX_STEP ints = 64 KB

    hipMemsetAsync(out, 0, (size_t)out_size * sizeof(float), stream);
    find_onehot_kernel<<<BATCH * MAX_STEP, 256, 0, stream>>>(batch, qa);
    loss_kernel<<<BATCH, 256, 0, stream>>>(pred, target_q, target_label, qa, out);
}

// Round 2
// 733.354 us; speedup vs baseline: 1.0499x; 1.0499x over previous
//
#include <hip/hip_runtime.h>
#include <limits.h>

#define NUM_Q    4096
#define MAX_STEP 256
#define BATCH    64
#define TWOQ     8192   // 2*NUM_Q
#define ROWS     (BATCH * MAX_STEP)   // 16384
#define VEC_PER_ROW (TWOQ / 4)        // 2048 float4
#define ITERS    (VEC_PER_ROW / 64)   // 32 iters of 64 lanes x float4

// Kernel 1: ONE WAVE per (b,s) row of batch [B,S,2Q]. Scan for the single
// nonzero (one-hot) with early exit via wave ballot; values are 0.0 or 1.0 so
// sum>0 detects a hit exactly. qa[row] = idx in [0,8192) or -1 (padding row).
// Early exit cuts expected read from 32 KB/row to ~16 KB/row.
__global__ void __launch_bounds__(256) find_onehot_kernel(
        const float* __restrict__ batch, int* __restrict__ qa) {
    const int gtid = blockIdx.x * blockDim.x + threadIdx.x;
    const int row  = gtid >> 6;        // global wave id = row
    const int lane = gtid & 63;
    if (row >= ROWS) return;

    const float4* rp = (const float4*)(batch + (size_t)row * TWOQ);

    int found = -1;
    float4 v = rp[lane];               // iter 0 in flight
    for (int it = 0; it < ITERS; ++it) {
        float4 nv;
        if (it + 1 < ITERS) nv = rp[(it + 1) * 64 + lane];  // prefetch next 1KB
        const float s = v.x + v.y + v.z + v.w;              // 0.0 or 1.0
        const unsigned long long m = __ballot(s > 0.0f);    // wave-uniform
        if (m) {
            const int src = __ffsll(m) - 1;
            int idx = 0;
            if (lane == src) {
                const int base = (it * 64 + lane) * 4;
                idx = (v.x != 0.f) ? base
                    : (v.y != 0.f) ? base + 1
                    : (v.z != 0.f) ? base + 2
                                   : base + 3;
            }
            found = __shfl(idx, src);
            break;
        }
        v = nv;
    }
    if (lane == 0) qa[row] = found;
}

__device__ __forceinline__ float bce(float p, float a) {
    // matches torch BCELoss: logs clamped at -100. logf(0) = -inf -> clamped.
    float lp  = fmaxf(logf(p), -100.0f);
    float l1p = fmaxf(log1pf(-p), -100.0f);
    return -(a * lp + (1.0f - a) * l1p);
}

// Kernel 2: one block per student b. Finds trim index i, sums BCE over s>=i,
// adds tail term, divides by n = 256 - i, atomically accumulates into out[0].
__global__ void __launch_bounds__(256) loss_kernel(
        const float* __restrict__ pred,
        const float* __restrict__ target_q,
        const float* __restrict__ target_label,
        const int* __restrict__ qa,
        float* __restrict__ out) {
    const int b = blockIdx.x;
    const int t = threadIdx.x;
    const int SM1 = MAX_STEP - 1;  // 255

    __shared__ int   smin[256];
    __shared__ float ssum[256];

    // step s = t (covers 0..254), uses qa[b, s+1].
    int   idx = -1;
    float p   = 0.0f;
    float a   = 0.0f;
    if (t < SM1) {
        idx = qa[b * MAX_STEP + t + 1];
        if (idx >= 0) {
            const int qid = idx & (NUM_Q - 1);
            p = pred[((size_t)b * MAX_STEP + t) * NUM_Q + qid];
            a = (idx < NUM_Q) ? 1.0f : 0.0f;
        }
    }

    // i = first s with p > 0 (pred >= 0.01 so any valid gather gives p > 0).
    // argmax of all-false -> 0.
    smin[t] = (t < SM1 && idx >= 0 && p > 0.0f) ? t : INT_MAX;
    __syncthreads();
    #pragma unroll
    for (int off = 128; off > 0; off >>= 1) {
        if (t < off) smin[t] = min(smin[t], smin[t + off]);
        __syncthreads();
    }
    const int i0 = (smin[0] == INT_MAX) ? 0 : smin[0];

    // seq_loss: sum BCE over masked steps s >= i0
    float v = 0.0f;
    if (t < SM1 && t >= i0) v = bce(p, a);
    ssum[t] = v;
    __syncthreads();
    #pragma unroll
    for (int off = 128; off > 0; off >>= 1) {
        if (t < off) ssum[t] += ssum[t + off];
        __syncthreads();
    }

    if (t == 0) {
        const float tail = bce(target_q[b], target_label[b]);
        const float n = (float)(MAX_STEP - i0);  // (S-1) - i + 1
        atomicAdd(out, (ssum[0] + tail) / n);
    }
}

extern "C" void kernel_launch(void* const* d_in, const int* in_sizes, int n_in,
                              void* d_out, int out_size, void* d_ws, size_t ws_size,
                              hipStream_t stream) {
    const float* pred         = (const float*)d_in[0];  // [B,S,Q]
    const float* target_q     = (const float*)d_in[1];  // [B,1]
    const float* batch        = (const float*)d_in[2];  // [B,S,2Q]
    const float* target_label = (const float*)d_in[3];  // [B]
    float* out = (float*)d_out;
    int*   qa  = (int*)d_ws;  // ROWS ints = 64 KB

    hipMemsetAsync(out, 0, (size_t)out_size * sizeof(float), stream);
    // one wave per row: ROWS waves = ROWS*64 threads, 256-thread blocks
    find_onehot_kernel<<<(ROWS * 64) / 256, 256, 0, stream>>>(batch, qa);
    loss_kernel<<<BATCH, 256, 0, stream>>>(pred, target_q, target_label, qa, out);
}